// Round 5
// baseline (247.462 us; speedup 1.0000x reference)
//
#include <hip/hip_runtime.h>
#include <math.h>

// B=4, S=4096, D=2048, E=64, K=2
#define NTOK    16384
#define DDIM    2048
#define NEXP    64
#define PSTRIDE (NTOK * NEXP)
#define KP      256              // k per phase
#define PHASES  (DDIM / KP)      // 8
#define ROWP    (KP + 8)         // padded LDS row stride (fp16)
#define HOFF    (NEXP * ROWP)    // lo-plane offset (fp16 elems)

typedef _Float16 half8   __attribute__((ext_vector_type(8)));
typedef _Float16 half4   __attribute__((ext_vector_type(4)));
typedef float    floatx4 __attribute__((ext_vector_type(4)));

// ---------------------------------------------------------------------------
// Fused router. Block = 32 tokens, 4 waves: wave (t,h) = token-half t,
// k-half h of each 256-k phase. Grid 512 = 2 blocks/CU -> 8 waves/CU.
// Per phase: stage W slice as hi/lo fp16 in LDS (vmcnt = x only in the MFMA
// loop), batch-issue the phase's 8 x-loads BEFORE the barrier so HBM latency
// overlaps staging. Register K-accumulate; LDS reduce h=1 -> h=0; wave-local
// softmax + stable top-2.
// ---------------------------------------------------------------------------
__global__ __launch_bounds__(256, 2) void router_kernel(
    const float* __restrict__ x,
    const float* __restrict__ W,
    const float* __restrict__ bias,
    float* __restrict__ out)
{
    __shared__ _Float16 wlds[2 * NEXP * ROWP];   // 67,584 B -> 2 blocks/CU

    const int tid  = threadIdx.x;
    const int lane = tid & 63;
    const int wv   = tid >> 6;
    const int t    = wv >> 1;          // token half: 0,1
    const int h    = wv & 1;           // k half within phase
    const int t0   = blockIdx.x * 32 + t * 16;
    const int mrow = lane & 15;        // A token row / B expert col
    const int quad = lane >> 4;

    floatx4 acc_hh[4], acc_md[4];
#pragma unroll
    for (int j = 0; j < 4; ++j) { acc_hh[j] = (floatx4)0.0f; acc_md[j] = (floatx4)0.0f; }

    const float* xrow = x + (size_t)(t0 + mrow) * DDIM + h * 128 + quad * 8;
    const _Float16* bfrag = &wlds[mrow * ROWP + h * 128 + quad * 8];

    for (int p = 0; p < PHASES; ++p) {
        const int k0 = p * KP;

        __syncthreads();   // all waves done reading previous slice

        // ---- stage W[:, k0:k0+256] as hi / lo*2^11 fp16 into padded LDS ----
        // 64 x 256 floats = 4096 float4 = 256 thr x 16
#pragma unroll
        for (int i = 0; i < 16; ++i) {
            const int f  = tid + (i << 8);
            const int e  = f >> 6;                 // expert row
            const int kc = (f & 63) << 2;          // k within slice
            floatx4 w4 = *(const floatx4*)&W[(size_t)e * DDIM + k0 + kc];
            half4 h4, l4;
#pragma unroll
            for (int c = 0; c < 4; ++c) {
                float wvv = w4[c];
                _Float16 hh = (_Float16)wvv;
                h4[c] = hh;
                l4[c] = (_Float16)((wvv - (float)hh) * 2048.0f);
            }
            *((half4*)&wlds[e * ROWP + kc])        = h4;
            *((half4*)&wlds[HOFF + e * ROWP + kc]) = l4;
        }

        // ---- batch-issue this phase's x loads (independent of LDS) ----
        const float* xp = xrow + k0;
        floatx4 xv[8];
#pragma unroll
        for (int s = 0; s < 4; ++s) {
            xv[2 * s]     = *(const floatx4*)(xp + s * 32);
            xv[2 * s + 1] = *(const floatx4*)(xp + s * 32 + 4);
        }

        __syncthreads();   // slice visible

        // ---- 4 MFMA k-steps over this wave's 128-k sub-range ----
#pragma unroll
        for (int s = 0; s < 4; ++s) {
            half8 a_hi, a_lo;
#pragma unroll
            for (int i = 0; i < 4; ++i) {
                float fv = xv[2 * s][i];
                _Float16 hh = (_Float16)fv;
                a_hi[i] = hh;
                a_lo[i] = (_Float16)((fv - (float)hh) * 2048.0f);
            }
#pragma unroll
            for (int i = 0; i < 4; ++i) {
                float fv = xv[2 * s + 1][i];
                _Float16 hh = (_Float16)fv;
                a_hi[4 + i] = hh;
                a_lo[4 + i] = (_Float16)((fv - (float)hh) * 2048.0f);
            }

#pragma unroll
            for (int j = 0; j < 4; ++j) {
                const int ro = j * 16 * ROWP + s * 32;
                half8 bh = *(const half8*)(bfrag + ro);
                half8 bl = *(const half8*)(bfrag + HOFF + ro);
                acc_hh[j] = __builtin_amdgcn_mfma_f32_16x16x32_f16(a_hi, bh, acc_hh[j], 0, 0, 0);
                acc_md[j] = __builtin_amdgcn_mfma_f32_16x16x32_f16(a_hi, bl, acc_md[j], 0, 0, 0);
                acc_md[j] = __builtin_amdgcn_mfma_f32_16x16x32_f16(a_lo, bh, acc_md[j], 0, 0, 0);
            }
        }
    }

    // ---- cross-wave K reduction (h=1 -> h=0) reusing the W LDS buffer ----
    __syncthreads();
    float* rbuf = (float*)wlds;        // 4096 floats = 16 KB, lane-major
    if (h == 1) {
#pragma unroll
        for (int j = 0; j < 4; ++j)
#pragma unroll
            for (int r = 0; r < 4; ++r) {
                rbuf[t * 2048 +        (j * 4 + r) * 64 + lane] = acc_hh[j][r];
                rbuf[t * 2048 + 1024 + (j * 4 + r) * 64 + lane] = acc_md[j][r];
            }
    }
    __syncthreads();
    if (h == 1) return;

#pragma unroll
    for (int j = 0; j < 4; ++j)
#pragma unroll
        for (int r = 0; r < 4; ++r) {
            acc_hh[j][r] += rbuf[t * 2048 +        (j * 4 + r) * 64 + lane];
            acc_md[j][r] += rbuf[t * 2048 + 1024 + (j * 4 + r) * 64 + lane];
        }

    // ---- epilogue: lane owns tokens t0 + quad*4 + r, experts j*16 + mrow ----
    const int c = mrow;
    float logit[4][4];
#pragma unroll
    for (int j = 0; j < 4; ++j) {
        const float bj = bias[j * 16 + c];
#pragma unroll
        for (int r = 0; r < 4; ++r)
            logit[j][r] = acc_hh[j][r] + acc_md[j][r] * (1.0f / 2048.0f) + bj;
    }

#pragma unroll
    for (int r = 0; r < 4; ++r) {
        const int trow = t0 + quad * 4 + r;

        float m = logit[0][r];
#pragma unroll
        for (int j = 1; j < 4; ++j) m = fmaxf(m, logit[j][r]);
#pragma unroll
        for (int off = 1; off <= 8; off <<= 1) m = fmaxf(m, __shfl_xor(m, off));

        float pj[4], s = 0.0f;
#pragma unroll
        for (int j = 0; j < 4; ++j) { pj[j] = __expf(logit[j][r] - m); s += pj[j]; }
#pragma unroll
        for (int off = 1; off <= 8; off <<= 1) s += __shfl_xor(s, off);
        const float rinv = 1.0f / s;

        // stable top-2 on logits (tie -> lower expert index)
        float v1 = -1e30f, v2 = -1e30f; int i1 = -1, i2 = -1;
#pragma unroll
        for (int j = 0; j < 4; ++j) {
            float v = logit[j][r]; int e = j * 16 + c;
            if (v > v1 || (v == v1 && e < i1)) { v2 = v1; i2 = i1; v1 = v; i1 = e; }
            else if (v > v2 || (v == v2 && e < i2)) { v2 = v; i2 = e; }
        }
#pragma unroll
        for (int off = 1; off <= 8; off <<= 1) {
            float u1 = __shfl_xor(v1, off); int q1 = __shfl_xor(i1, off);
            float u2 = __shfl_xor(v2, off); int q2 = __shfl_xor(i2, off);
            if (u1 > v1 || (u1 == v1 && q1 < i1)) {
                if (v1 > u2 || (v1 == u2 && i1 < q2)) { v2 = v1; i2 = i1; }
                else                                   { v2 = u2; i2 = q2; }
                v1 = u1; i1 = q1;
            } else {
                if (u1 > v2 || (u1 == v2 && q1 < i2)) { v2 = u1; i2 = q1; }
            }
        }

#pragma unroll
        for (int j = 0; j < 4; ++j) {
            const int col = j * 16 + c;
            const size_t o = (size_t)trow * NEXP + col;
            out[o]           = (col == i1 || col == i2) ? 1.0f : 0.0f;
            out[PSTRIDE + o] = pj[j] * rinv;
        }
    }
}

extern "C" void kernel_launch(void* const* d_in, const int* in_sizes, int n_in,
                              void* d_out, int out_size, void* d_ws, size_t ws_size,
                              hipStream_t stream) {
    const float* x = (const float*)d_in[0];   // [4,4096,2048] f32
    const float* W = (const float*)d_in[1];   // [64,2048] f32
    const float* b = (const float*)d_in[2];   // [64] f32
    (void)in_sizes; (void)n_in; (void)out_size; (void)d_ws; (void)ws_size;
    float* out = (float*)d_out;               // [masks | probs]

    hipLaunchKernelGGL(router_kernel, dim3(NTOK / 32), dim3(256), 0, stream, x, W, b, out);
}

// Round 6
// 215.583 us; speedup vs baseline: 1.1479x; 1.1479x over previous
//
#include <hip/hip_runtime.h>
#include <math.h>

// B=4, S=4096, D=2048, E=64, K=2
#define NTOK    16384
#define DDIM    2048
#define NEXP    64
#define PSTRIDE (NTOK * NEXP)
#define KP      256                 // k per phase
#define NPH     8                   // phases
#define ROWH    264                 // padded LDS row stride (halves): 528B = 2-way banks only
#define PLANE   (NEXP * ROWH)       // halves per (hi|lo) plane = 16896
#define SLICE   32768               // halves per d_ws phase slice: [hi 64*256][lo 64*256]

typedef _Float16 half8   __attribute__((ext_vector_type(8)));
typedef _Float16 half4   __attribute__((ext_vector_type(4)));
typedef float    floatx4 __attribute__((ext_vector_type(4)));

// ---------------------------------------------------------------------------
// W (fp32, [64][2048]) -> slice-major hi/lo fp16 in d_ws:
//   ws[p*SLICE + e*256 + kl]          = hi
//   ws[p*SLICE + 16384 + e*256 + kl]  = lo * 2^11
// so each phase's 64 KB staging source is contiguous.
// ---------------------------------------------------------------------------
__global__ __launch_bounds__(256) void wconv_kernel(
    const float* __restrict__ W, _Float16* __restrict__ ws)
{
    const int idx4 = blockIdx.x * 256 + threadIdx.x;   // 32768 float4-groups
    const int e    = idx4 >> 9;                        // 512 groups per expert row
    const int kg   = (idx4 & 511) << 2;
    floatx4 w4 = *(const floatx4*)&W[(size_t)e * DDIM + kg];
    half4 h4, l4;
#pragma unroll
    for (int c = 0; c < 4; ++c) {
        float wv = w4[c];
        _Float16 h = (_Float16)wv;
        h4[c] = h;
        l4[c] = (_Float16)((wv - (float)h) * 2048.0f);
    }
    const int p = kg >> 8, kl = kg & 255;
    _Float16* dst = ws + (size_t)p * SLICE + e * 256 + kl;
    *(half4*)dst           = h4;
    *(half4*)(dst + 16384) = l4;
}

// ---------------------------------------------------------------------------
// Fused router. Block = 64 tokens (4 waves x 16), full K, 8 phases.
// Software pipeline: at phase p, FIRST issue x(p+1) (regs) and W(p+1) (regs),
// THEN compute phase p (B from LDS buf[p&1]), then ds_write W(p+1) into the
// alternate LDS buffer, one barrier. Loads always have a full compute phase
// in flight before the barrier drain. Wave-local softmax + stable top-2.
// ---------------------------------------------------------------------------
__global__ __launch_bounds__(256, 1) void router_kernel(
    const float* __restrict__ x,
    const _Float16* __restrict__ ws,
    const float* __restrict__ bias,
    float* __restrict__ out)
{
    __shared__ _Float16 lds[2][2 * PLANE];   // 135,168 B -> 1 block/CU

    const int tid  = threadIdx.x;
    const int lane = tid & 63;
    const int wid  = tid >> 6;
    const int t0   = blockIdx.x * 64 + wid * 16;
    const int mrow = lane & 15;      // A token row / B expert col
    const int quad = lane >> 4;

    floatx4 acc_hh[4], acc_md[4];
#pragma unroll
    for (int j = 0; j < 4; ++j) { acc_hh[j] = (floatx4)0.0f; acc_md[j] = (floatx4)0.0f; }

    const float* xrow = x + (size_t)(t0 + mrow) * DDIM + quad * 8;

    floatx4 xc[16], xn[16];   // current / next phase x (16 float4 each)
    half8   wn[16];           // next phase W staging registers

    // ---- prologue: phase-0 x and W ----
#pragma unroll
    for (int s = 0; s < 8; ++s) {
        xc[2 * s]     = *(const floatx4*)(xrow + s * 32);
        xc[2 * s + 1] = *(const floatx4*)(xrow + s * 32 + 4);
    }
#pragma unroll
    for (int i = 0; i < 16; ++i)
        wn[i] = *(const half8*)(ws + (size_t)(tid + i * 256) * 8);
#pragma unroll
    for (int i = 0; i < 16; ++i) {
        const int c16 = tid + i * 256;
        const int pl  = c16 >> 11, r = c16 & 2047;
        *(half8*)&lds[0][pl * PLANE + (r >> 5) * ROWH + ((r & 31) << 3)] = wn[i];
    }
    __syncthreads();

    const _Float16* lr = &lds[0][0];
    _Float16*       lw = &lds[1][0];

    for (int p = 0; p < NPH; ++p) {
        // ---- issue next phase's loads FIRST (in flight during compute) ----
        if (p < NPH - 1) {
            const float* xp = xrow + (p + 1) * KP;
#pragma unroll
            for (int s = 0; s < 8; ++s) {
                xn[2 * s]     = *(const floatx4*)(xp + s * 32);
                xn[2 * s + 1] = *(const floatx4*)(xp + s * 32 + 4);
            }
            const _Float16* wsrc = ws + (size_t)(p + 1) * SLICE;
#pragma unroll
            for (int i = 0; i < 16; ++i)
                wn[i] = *(const half8*)(wsrc + (size_t)(tid + i * 256) * 8);
        }

        // ---- compute phase p: 8 k-steps, B from LDS (lgkmcnt queue) ----
#pragma unroll
        for (int s = 0; s < 8; ++s) {
            half8 a_hi, a_lo;
#pragma unroll
            for (int i = 0; i < 4; ++i) {
                float fv = xc[2 * s][i];
                _Float16 h = (_Float16)fv;
                a_hi[i] = h;
                a_lo[i] = (_Float16)((fv - (float)h) * 2048.0f);
            }
#pragma unroll
            for (int i = 0; i < 4; ++i) {
                float fv = xc[2 * s + 1][i];
                _Float16 h = (_Float16)fv;
                a_hi[4 + i] = h;
                a_lo[4 + i] = (_Float16)((fv - (float)h) * 2048.0f);
            }
#pragma unroll
            for (int j = 0; j < 4; ++j) {
                const _Float16* bb = lr + (j * 16 + mrow) * ROWH + s * 32 + quad * 8;
                half8 bh = *(const half8*)bb;
                half8 bl = *(const half8*)(bb + PLANE);
                acc_hh[j] = __builtin_amdgcn_mfma_f32_16x16x32_f16(a_hi, bh, acc_hh[j], 0, 0, 0);
                acc_md[j] = __builtin_amdgcn_mfma_f32_16x16x32_f16(a_hi, bl, acc_md[j], 0, 0, 0);
                acc_md[j] = __builtin_amdgcn_mfma_f32_16x16x32_f16(a_lo, bh, acc_md[j], 0, 0, 0);
            }
        }

        // ---- commit next phase: LDS write + register rotate + buffer swap ----
        if (p < NPH - 1) {
#pragma unroll
            for (int i = 0; i < 16; ++i) {
                const int c16 = tid + i * 256;
                const int pl  = c16 >> 11, r = c16 & 2047;
                *(half8*)&lw[pl * PLANE + (r >> 5) * ROWH + ((r & 31) << 3)] = wn[i];
            }
#pragma unroll
            for (int i = 0; i < 16; ++i) xc[i] = xn[i];
            _Float16* t = (_Float16*)lr; lr = lw; lw = t;
        }
        __syncthreads();
    }

    // ---- wave-local epilogue: lane owns tokens t0+quad*4+r, experts j*16+mrow ----
    const int c = mrow;
    float logit[4][4];
#pragma unroll
    for (int j = 0; j < 4; ++j) {
        const float bj = bias[j * 16 + c];
#pragma unroll
        for (int r = 0; r < 4; ++r)
            logit[j][r] = acc_hh[j][r] + acc_md[j][r] * (1.0f / 2048.0f) + bj;
    }

#pragma unroll
    for (int r = 0; r < 4; ++r) {
        const int trow = t0 + quad * 4 + r;

        float m = logit[0][r];
#pragma unroll
        for (int j = 1; j < 4; ++j) m = fmaxf(m, logit[j][r]);
#pragma unroll
        for (int off = 1; off <= 8; off <<= 1) m = fmaxf(m, __shfl_xor(m, off));

        float pj[4], s = 0.0f;
#pragma unroll
        for (int j = 0; j < 4; ++j) { pj[j] = __expf(logit[j][r] - m); s += pj[j]; }
#pragma unroll
        for (int off = 1; off <= 8; off <<= 1) s += __shfl_xor(s, off);
        const float rinv = 1.0f / s;

        // stable top-2 on logits (tie -> lower expert index)
        float v1 = -1e30f, v2 = -1e30f; int i1 = -1, i2 = -1;
#pragma unroll
        for (int j = 0; j < 4; ++j) {
            float v = logit[j][r]; int e = j * 16 + c;
            if (v > v1 || (v == v1 && e < i1)) { v2 = v1; i2 = i1; v1 = v; i1 = e; }
            else if (v > v2 || (v == v2 && e < i2)) { v2 = v; i2 = e; }
        }
#pragma unroll
        for (int off = 1; off <= 8; off <<= 1) {
            float u1 = __shfl_xor(v1, off); int q1 = __shfl_xor(i1, off);
            float u2 = __shfl_xor(v2, off); int q2 = __shfl_xor(i2, off);
            if (u1 > v1 || (u1 == v1 && q1 < i1)) {
                if (v1 > u2 || (v1 == u2 && i1 < q2)) { v2 = v1; i2 = i1; }
                else                                   { v2 = u2; i2 = q2; }
                v1 = u1; i1 = q1;
            } else {
                if (u1 > v2 || (u1 == v2 && q1 < i2)) { v2 = u1; i2 = q1; }
            }
        }

#pragma unroll
        for (int j = 0; j < 4; ++j) {
            const int col = j * 16 + c;
            const size_t o = (size_t)trow * NEXP + col;
            out[o]           = (col == i1 || col == i2) ? 1.0f : 0.0f;
            out[PSTRIDE + o] = pj[j] * rinv;
        }
    }
}

extern "C" void kernel_launch(void* const* d_in, const int* in_sizes, int n_in,
                              void* d_out, int out_size, void* d_ws, size_t ws_size,
                              hipStream_t stream) {
    const float* x = (const float*)d_in[0];   // [4,4096,2048] f32
    const float* W = (const float*)d_in[1];   // [64,2048] f32
    const float* b = (const float*)d_in[2];   // [64] f32
    (void)in_sizes; (void)n_in; (void)out_size; (void)ws_size;
    float* out = (float*)d_out;               // [masks | probs]

    _Float16* ws = (_Float16*)d_ws;           // 8 slices x 32768 halves = 512 KB

    hipLaunchKernelGGL(wconv_kernel, dim3(128), dim3(256), 0, stream, W, ws);
    hipLaunchKernelGGL(router_kernel, dim3(NTOK / 64), dim3(256), 0, stream, x, ws, b, out);
}

// Round 7
// 200.289 us; speedup vs baseline: 1.2355x; 1.0764x over previous
//
#include <hip/hip_runtime.h>
#include <math.h>

// B=4, S=4096, D=2048, E=64, K=2
#define NTOK    16384
#define DDIM    2048
#define NEXP    64
#define PSTRIDE (NTOK * NEXP)
#define KP      128                 // k per phase
#define NPH     16                  // phases
#define PLANE_H 8192                // halves per plane (64 e x 128 k)
#define SLICE_B 32768               // bytes per slice (hi plane 16 KB + lo plane 16 KB)

#define AS1 __attribute__((address_space(1)))
#define AS3 __attribute__((address_space(3)))

typedef _Float16 half8   __attribute__((ext_vector_type(8)));
typedef float    floatx4 __attribute__((ext_vector_type(4)));

// ---------------------------------------------------------------------------
// W (fp32 [64][2048]) -> d_ws, slice-major, LDS-linear chunk order with XOR
// swizzle: slice p, linear 16B-chunk L = plane*1024 + e*16 + c', where the
// chunk holds source k-chunk c = c' ^ (e&7). Staging in the router is then a
// pure linear DMA; ds_read banking is conflict-light.
// ---------------------------------------------------------------------------
__global__ __launch_bounds__(256) void wconv_kernel(
    const float* __restrict__ W, _Float16* __restrict__ ws)
{
    const int g     = blockIdx.x * 256 + threadIdx.x;   // 32768 chunks total
    const int p     = g >> 11;
    const int L     = g & 2047;
    const int plane = L >> 10;
    const int e     = (L >> 4) & 63;
    const int cp    = L & 15;
    const int c     = cp ^ (e & 7);
    const int k     = (p << 7) + (c << 3);

    const float* src = &W[(size_t)e * DDIM + k];
    floatx4 w0 = *(const floatx4*)src;
    floatx4 w1 = *(const floatx4*)(src + 4);

    half8 o;
#pragma unroll
    for (int i = 0; i < 4; ++i) {
        float f0 = w0[i], f1 = w1[i];
        _Float16 h0 = (_Float16)f0, h1 = (_Float16)f1;
        if (plane == 0) { o[i] = h0; o[4 + i] = h1; }
        else {
            o[i]     = (_Float16)((f0 - (float)h0) * 2048.0f);
            o[4 + i] = (_Float16)((f1 - (float)h1) * 2048.0f);
        }
    }
    *(half8*)((char*)ws + (size_t)g * 16) = o;
}

// ---------------------------------------------------------------------------
// Fused router. Block = 32 tokens, waves (t,h) = token-half x k-half.
// Grid 512 = 2 blocks/CU -> 8 waves/CU. 16 phases of 128 k, double-buffered
// 32 KB W slices staged by global_load_lds (width 16) issued one phase ahead
// together with the x prefetch; compute reads B from LDS (lgkm queue).
// LDS reduce h=1 -> h=0 of pre-combined logits; wave-local softmax + top-2.
// ---------------------------------------------------------------------------
__global__ __launch_bounds__(256, 2) void router_kernel(
    const float* __restrict__ x,
    const _Float16* __restrict__ ws,
    const float* __restrict__ bias,
    float* __restrict__ out)
{
    __shared__ _Float16 lds[2][SLICE_B / 2];   // 2 x 32 KB

    const int tid  = threadIdx.x;
    const int lane = tid & 63;
    const int wid  = tid >> 6;
    const int t    = wid >> 1;         // token half
    const int h    = wid & 1;          // k half of each phase
    const int t0   = blockIdx.x * 32 + t * 16;
    const int mrow = lane & 15;        // A token row / B expert col
    const int quad = lane >> 4;

    floatx4 acc_hh[4], acc_md[4];
#pragma unroll
    for (int j = 0; j < 4; ++j) { acc_hh[j] = (floatx4)0.0f; acc_md[j] = (floatx4)0.0f; }

    // x: row (t0+mrow), phase-p k base = p*128 + h*64 + quad*8
    const float* xrow = x + (size_t)(t0 + mrow) * DDIM + h * 64 + quad * 8;

    // staging DMA: wave wid copies slice bytes [wid*8192, wid*8192+8192)
    const char* gslice0 = (const char*)ws;
    char*       lbase[2] = { (char*)&lds[0][0] + wid * 8192,
                             (char*)&lds[1][0] + wid * 8192 };

#define STAGE(P, BUF)                                                          \
    {                                                                          \
        const char* gsrc = gslice0 + (size_t)(P) * SLICE_B + wid * 8192 + lane * 16; \
        char*       ldst = lbase[BUF];                                         \
        _Pragma("unroll")                                                      \
        for (int i = 0; i < 8; ++i)                                            \
            __builtin_amdgcn_global_load_lds(                                  \
                (const AS1 unsigned int*)(const void*)(gsrc + i * 1024),       \
                (AS3 unsigned int*)(void*)(ldst + i * 1024), 16, 0, 0);        \
    }

    floatx4 xc[4], xn[4];

    // ---- prologue: phase 0 ----
    STAGE(0, 0);
#pragma unroll
    for (int s = 0; s < 2; ++s) {
        xc[2 * s]     = *(const floatx4*)(xrow + s * 32);
        xc[2 * s + 1] = *(const floatx4*)(xrow + s * 32 + 4);
    }
    __syncthreads();   // barrier drains the DMA (vmcnt(0))

#pragma unroll 2
    for (int p = 0; p < NPH; ++p) {
        // ---- issue next phase's DMA + x prefetch FIRST ----
        if (p < NPH - 1) {
            STAGE(p + 1, (p + 1) & 1);
            const float* xp = xrow + (p + 1) * KP;
#pragma unroll
            for (int s = 0; s < 2; ++s) {
                xn[2 * s]     = *(const floatx4*)(xp + s * 32);
                xn[2 * s + 1] = *(const floatx4*)(xp + s * 32 + 4);
            }
        }

        // ---- compute phase p: 2 k-steps of 32, B from lds[p&1] ----
        const _Float16* lb = &lds[p & 1][0];
#pragma unroll
        for (int s = 0; s < 2; ++s) {
            half8 a_hi, a_lo;
#pragma unroll
            for (int i = 0; i < 4; ++i) {
                float fv = xc[2 * s][i];
                _Float16 hh = (_Float16)fv;
                a_hi[i] = hh;
                a_lo[i] = (_Float16)((fv - (float)hh) * 2048.0f);
            }
#pragma unroll
            for (int i = 0; i < 4; ++i) {
                float fv = xc[2 * s + 1][i];
                _Float16 hh = (_Float16)fv;
                a_hi[4 + i] = hh;
                a_lo[4 + i] = (_Float16)((fv - (float)hh) * 2048.0f);
            }
#pragma unroll
            for (int j = 0; j < 4; ++j) {
                const int e   = j * 16 + mrow;
                const int c   = h * 8 + s * 4 + quad;          // 16B chunk in row
                const int off = e * 128 + ((c ^ (e & 7)) << 3); // halves
                half8 bh = *(const half8*)(lb + off);
                half8 bl = *(const half8*)(lb + PLANE_H + off);
                acc_hh[j] = __builtin_amdgcn_mfma_f32_16x16x32_f16(a_hi, bh, acc_hh[j], 0, 0, 0);
                acc_md[j] = __builtin_amdgcn_mfma_f32_16x16x32_f16(a_hi, bl, acc_md[j], 0, 0, 0);
                acc_md[j] = __builtin_amdgcn_mfma_f32_16x16x32_f16(a_lo, bh, acc_md[j], 0, 0, 0);
            }
        }

        if (p < NPH - 1) {
#pragma unroll
            for (int i = 0; i < 4; ++i) xc[i] = xn[i];
        }
        __syncthreads();   // drains next phase's DMA + xn; swaps buffers
    }

    // ---- combine planes, reduce h=1 -> h=0 through LDS ----
    float lg[4][4];
#pragma unroll
    for (int j = 0; j < 4; ++j)
#pragma unroll
        for (int r = 0; r < 4; ++r)
            lg[j][r] = acc_hh[j][r] + acc_md[j][r] * (1.0f / 2048.0f);

    float* rbuf = (float*)&lds[0][0];   // 2 KB used per t, lane-major
    if (h == 1) {
#pragma unroll
        for (int j = 0; j < 4; ++j)
#pragma unroll
            for (int r = 0; r < 4; ++r)
                rbuf[t * 1024 + (j * 4 + r) * 64 + lane] = lg[j][r];
    }
    __syncthreads();
    if (h == 1) return;

#pragma unroll
    for (int j = 0; j < 4; ++j) {
        const float bj = bias[j * 16 + mrow];
#pragma unroll
        for (int r = 0; r < 4; ++r)
            lg[j][r] += rbuf[t * 1024 + (j * 4 + r) * 64 + lane] + bj;
    }

    // ---- epilogue: lane owns tokens t0 + quad*4 + r, experts j*16 + mrow ----
    const int c = mrow;
#pragma unroll
    for (int r = 0; r < 4; ++r) {
        const int trow = t0 + quad * 4 + r;

        float m = lg[0][r];
#pragma unroll
        for (int j = 1; j < 4; ++j) m = fmaxf(m, lg[j][r]);
#pragma unroll
        for (int off = 1; off <= 8; off <<= 1) m = fmaxf(m, __shfl_xor(m, off));

        float pj[4], s = 0.0f;
#pragma unroll
        for (int j = 0; j < 4; ++j) { pj[j] = __expf(lg[j][r] - m); s += pj[j]; }
#pragma unroll
        for (int off = 1; off <= 8; off <<= 1) s += __shfl_xor(s, off);
        const float rinv = 1.0f / s;

        // stable top-2 on logits (tie -> lower expert index)
        float v1 = -1e30f, v2 = -1e30f; int i1 = -1, i2 = -1;
#pragma unroll
        for (int j = 0; j < 4; ++j) {
            float v = lg[j][r]; int e = j * 16 + c;
            if (v > v1 || (v == v1 && e < i1)) { v2 = v1; i2 = i1; v1 = v; i1 = e; }
            else if (v > v2 || (v == v2 && e < i2)) { v2 = v; i2 = e; }
        }
#pragma unroll
        for (int off = 1; off <= 8; off <<= 1) {
            float u1 = __shfl_xor(v1, off); int q1 = __shfl_xor(i1, off);
            float u2 = __shfl_xor(v2, off); int q2 = __shfl_xor(i2, off);
            if (u1 > v1 || (u1 == v1 && q1 < i1)) {
                if (v1 > u2 || (v1 == u2 && i1 < q2)) { v2 = v1; i2 = i1; }
                else                                   { v2 = u2; i2 = q2; }
                v1 = u1; i1 = q1;
            } else {
                if (u1 > v2 || (u1 == v2 && q1 < i2)) { v2 = u1; i2 = q1; }
            }
        }

#pragma unroll
        for (int j = 0; j < 4; ++j) {
            const int col = j * 16 + c;
            const size_t o = (size_t)trow * NEXP + col;
            out[o]           = (col == i1 || col == i2) ? 1.0f : 0.0f;
            out[PSTRIDE + o] = pj[j] * rinv;
        }
    }
}

extern "C" void kernel_launch(void* const* d_in, const int* in_sizes, int n_in,
                              void* d_out, int out_size, void* d_ws, size_t ws_size,
                              hipStream_t stream) {
    const float* x = (const float*)d_in[0];   // [4,4096,2048] f32
    const float* W = (const float*)d_in[1];   // [64,2048] f32
    const float* b = (const float*)d_in[2];   // [64] f32
    (void)in_sizes; (void)n_in; (void)out_size; (void)ws_size;
    float* out = (float*)d_out;               // [masks | probs]

    _Float16* ws = (_Float16*)d_ws;           // 16 slices x 32 KB = 512 KB

    hipLaunchKernelGGL(wconv_kernel, dim3(128), dim3(256), 0, stream, W, ws);
    hipLaunchKernelGGL(router_kernel, dim3(NTOK / 32), dim3(256), 0, stream, x, ws, b, out);
}